// Round 15
// baseline (80.057 us; speedup 1.0000x reference)
//
#include <hip/hip_runtime.h>

// Greedy NMS, M=16384 pts, radius 2.0, torch PairwiseDistance eps=1e-6.
// Output INT32: mask[16384] as 0/1, then count[1].
//
// Round 15: A/B on K3 (K1 bin25 + K2 wscan identical to r11..r14).
//  K3 solve_gs (1x1024): active entries compacted into 4 DESCENDING-SCORE
//  bands (suppressors always have higher score), swept band-major with
//  in-place LDS writes (chaotic Gauss-Seidel) -> ~EPT levels of propagation
//  per sweep instead of 1. Convergence certificate unchanged
//  (__syncthreads_count(any)==0 => f(S)=S => unique DAG fixpoint).
//  Banding is a heuristic for SPEED only; correctness is band-independent.

#define M_PTS    16384
#define RADIUS   2.0f
#define EPS_D    1e-6f
#define GRID_N   25        // 4 m cells over 100 m scene
#define NCELLS   (GRID_N * GRID_N * GRID_N)
#define CELL_CAP 12
#define K_NBR    12
#define CELLS_PB (GRID_N * GRID_N)        // 625 cells per bin-block
#define LIST_PB  (CELLS_PB * CELL_CAP)    // 7500 entries per bin-block
#define EPT      5
#define BANDS    4
#define BAND_CAP 1280                     // E[983]/band, sd~27 -> 11 sigma
#define ACT_PAD  (BANDS * BAND_CAP)       // 5120 = EPT * 1024
#define SENT     M_PTS                    // always-0 sentinel byte index

// ws layout (bytes):
//   [0,       262144) float4 pts[16384]
//   [262144,  324644) int    cell_cnt[15625]
//   [327680,  393216) int    cnt[16384]
//   [393216,  768216) ushort cell_list[15625*12]
//   [770048, 1163264) ushort nbr[16384*12]

__device__ __forceinline__ int cell_of(float v) {
  int c = (int)(v * 0.25f);
  return c < 0 ? 0 : (c > GRID_N - 1 ? GRID_N - 1 : c);
}

__device__ __forceinline__ bool edge_test(float4 pi, float4 pj, int j, int i) {
  // j earlier in argsort(-score, stable) AND torch-dist <= radius (exact math)
  bool earlier = (pj.w > pi.w) || ((pj.w == pi.w) && (j < i));
  if (!earlier) return false;
  float ddx = __fadd_rn(__fsub_rn(pi.x, pj.x), EPS_D);
  float ddy = __fadd_rn(__fsub_rn(pi.y, pj.y), EPS_D);
  float ddz = __fadd_rn(__fsub_rn(pi.z, pj.z), EPS_D);
  float d2 = __fadd_rn(__fadd_rn(__fmul_rn(ddx, ddx), __fmul_rn(ddy, ddy)),
                       __fmul_rn(ddz, ddz));
  return !(__fsqrt_rn(d2) > RADIUS);
}

// ---- K1: 25 blocks; block b owns all cells with cx==b (unchanged r11). ----
__global__ __launch_bounds__(1024) void bin25(
    const float* __restrict__ nodes, const float* __restrict__ score,
    float4* __restrict__ pts, int* __restrict__ cell_cnt,
    unsigned short* __restrict__ cell_list) {
  __shared__ int ccnt[CELLS_PB];              // 2.5 KB
  __shared__ unsigned short clist[LIST_PB];   // 15 KB
  const int tid = threadIdx.x;
  const int b   = blockIdx.x;
  if (tid < CELLS_PB) ccnt[tid] = 0;
  __syncthreads();

  for (int i = tid; i < M_PTS; i += 1024) {
    float x = nodes[3 * i + 0];
    if (cell_of(x) != b) continue;
    float y = nodes[3 * i + 1];
    float z = nodes[3 * i + 2];
    float s = score[i];
    pts[i] = make_float4(x, y, z, s);
    int lc = cell_of(y) * GRID_N + cell_of(z);
    int pos = atomicAdd(&ccnt[lc], 1);
    if (pos < CELL_CAP) clist[lc * CELL_CAP + pos] = (unsigned short)i;
  }
  __syncthreads();

  if (tid < CELLS_PB) {
    int v = ccnt[tid];
    cell_cnt[b * CELLS_PB + tid] = v > CELL_CAP ? CELL_CAP : v;
  }
  for (int e = tid; e < LIST_PB; e += 1024)
    cell_list[b * LIST_PB + e] = clist[e];
}

// ---- K2: 2 points/wave, one cell/lane (unchanged r10/r11). ----
__global__ __launch_bounds__(256) void wscan(
    const float4* __restrict__ pts, const int* __restrict__ cell_cnt,
    const unsigned short* __restrict__ cell_list,
    int* __restrict__ cnt, unsigned short* __restrict__ nbr) {
  const int tid  = threadIdx.x;
  const int lane = tid & 63;
  const int d    = lane & 31;
  const int half = lane >> 5;
  const int gwave = (blockIdx.x * 256 + tid) >> 6;
  const int i = gwave * 2 + half;

  const float4 pi = pts[i];
  int n = 0, cid = 0, m = 0, firstj = 0;
  if (d < 27) {
    int cx = cell_of(pi.x) + d / 9 - 1;
    int cy = cell_of(pi.y) + (d / 3) % 3 - 1;
    int cz = cell_of(pi.z) + d % 3 - 1;
    if (cx >= 0 && cx < GRID_N && cy >= 0 && cy < GRID_N &&
        cz >= 0 && cz < GRID_N) {
      cid = (cx * GRID_N + cy) * GRID_N + cz;
      m = cell_cnt[cid];
      for (int s = 0; s < m; ++s) {
        int j = cell_list[cid * CELL_CAP + s];
        if (edge_test(pi, pts[j], j, i)) { if (!n) firstj = j; ++n; }
      }
    }
  }
  int x = n;
#pragma unroll
  for (int off = 1; off < 32; off <<= 1) {
    int y = __shfl_up(x, off, 32);
    if (d >= off) x += y;
  }
  int excl = x - n;
  int tot = __shfl(x, 31, 32);
  if (n == 1) {
    if (excl < K_NBR) nbr[i * K_NBR + excl] = (unsigned short)firstj;
  } else if (n > 1) {
    int pos = excl;
    for (int s = 0; s < m && pos < K_NBR; ++s) {
      int j = cell_list[cid * CELL_CAP + s];
      if (edge_test(pi, pts[j], j, i)) {
        nbr[i * K_NBR + pos] = (unsigned short)j;
        ++pos;
      }
    }
  }
  if (d == 0) cnt[i] = tot > K_NBR ? K_NBR : tot;
}

// ---- K3: banded Gauss-Seidel fixpoint, 1024 threads, no volatile ----
__global__ __launch_bounds__(1024) void solve_gs(
    const float4* __restrict__ pts, const int* __restrict__ cnt,
    const unsigned short* __restrict__ nbr,
    int* __restrict__ out, int out_size) {
  __shared__ unsigned char mask[M_PTS + 4];  // +sentinel (index SENT == 0)
  __shared__ unsigned int act[ACT_PAD];      // 20 KB: k | (c<<16)
  __shared__ int bn[BANDS];
  __shared__ int total;

  const int tid = threadIdx.x;
  const int lane = tid & 63;
  if (tid == 0) total = 0;
  if (tid < BANDS) bn[tid] = 0;
  unsigned int* mask4 = (unsigned int*)mask;
  for (int w = tid; w < M_PTS / 4; w += 1024) mask4[w] = 0x01010101u;
  if (tid == 0) mask4[M_PTS / 4] = 0u;       // sentinel byte = 0
  for (int a = tid; a < ACT_PAD; a += 1024) act[a] = 0u;  // c=0 sentinels
  __syncthreads();

  // banded ballot compaction: band 0 = highest scores (N(0,1) quartiles).
  // Banding is heuristic only — any distribution still converges.
  bool ovf = false;
  for (int k = tid; k < M_PTS; k += 1024) {
    int c = cnt[k];
    if (c > K_NBR) c = K_NBR;
    float s = pts[k].w;
    int band = (s > 0.67448975f) ? 0 : (s > 0.0f) ? 1
             : (s > -0.67448975f) ? 2 : 3;
#pragma unroll
    for (int b = 0; b < BANDS; ++b) {
      bool sel = (c > 0) && (band == b);
      unsigned long long bal = __ballot(sel);
      if (!bal) continue;
      int wcnt = __popcll(bal);
      int wbase = 0;
      if (lane == 0) wbase = atomicAdd(&bn[b], wcnt);
      wbase = __shfl(wbase, 0, 64);
      if (sel) {
        int pos = wbase + __popcll(bal & ((1ull << lane) - 1ull));
        if (pos < BAND_CAP) act[b * BAND_CAP + pos] = (unsigned)k | ((unsigned)c << 16);
        else ovf = true;
      }
    }
  }
  __syncthreads();
  bool ok = (bn[0] <= BAND_CAP) && (bn[1] <= BAND_CAP) &&
            (bn[2] <= BAND_CAP) && (bn[3] <= BAND_CAP) && !ovf;
  ok = __syncthreads_count(ok) == 1024;      // all threads agree

  // stage entries: k|c, up to 3 neighbor ids (absent -> SENT), owner state
  unsigned ae[EPT];
  unsigned short r0[EPT], r1[EPT], r2[EPT];
  int cur[EPT];
#pragma unroll
  for (int e = 0; e < EPT; ++e) {
    unsigned v = act[tid + e * 1024];        // e-major: e ~ descending score
    ae[e] = v;
    int k = (int)(v & 0xFFFFu);
    int c = (int)(v >> 16);
    const unsigned short* row = nbr + (size_t)k * K_NBR;
    unsigned w = (c > 0) ? *(const unsigned int*)row : 0u;   // r0 | r1<<16
    r0[e] = (c > 0) ? (unsigned short)(w & 0xFFFFu) : (unsigned short)SENT;
    r1[e] = (c > 1) ? (unsigned short)(w >> 16)     : (unsigned short)SENT;
    r2[e] = (c > 2) ? row[2]                        : (unsigned short)SENT;
    cur[e] = 1;
  }
  __syncthreads();

  if (ok) {
    for (int it = 0; it < 96; ++it) {
      int any = 0;
      // per-e reads + in-place writes: Gauss-Seidel within the sweep.
      // e runs high-score bands first, so suppression propagates ~EPT
      // levels per sweep; cross-wave staleness is benign (chaotic iter).
#pragma unroll
      for (int e = 0; e < EPT; ++e) {
        unsigned v = ae[e];
        int c = (int)(v >> 16);
        int m0 = (int)mask[r0[e]];
        int m1 = (int)mask[r1[e]];
        int m2 = (int)mask[r2[e]];
        if (!c) continue;
        int kp = (m0 ^ 1) & (m1 ^ 1) & (m2 ^ 1);
        if (c > 3) {   // ~0.2% of actives: global tail
          int k = (int)(v & 0xFFFFu);
          const unsigned short* row = nbr + (size_t)k * K_NBR;
          for (int t = 3; t < c; ++t) kp &= (int)mask[row[t]] ^ 1;
        }
        if (kp != cur[e]) {
          cur[e] = kp;
          mask[v & 0xFFFFu] = (unsigned char)kp;   // single writer per entry
          any = 1;
        }
      }
      // no writes anywhere this sweep => state stable => unique fixpoint
      if (__syncthreads_count(any) == 0) break;
    }
  } else {
    // overflow fallback (statistically never): barriered global sweeps
    __shared__ int changed;
    for (int it = 0; it < 512; ++it) {
      if (tid == 0) changed = 0;
      __syncthreads();
      int any = 0;
      for (int k = tid; k < M_PTS; k += 1024) {
        int c = cnt[k]; if (c > K_NBR) c = K_NBR;
        if (!c) continue;
        int kp = 1;
        for (int t = 0; t < c; ++t) kp &= (int)mask[nbr[k * K_NBR + t]] ^ 1;
        if (kp != (int)mask[k]) { mask[k] = (unsigned char)kp; any = 1; }
      }
      if (any) changed = 1;
      __syncthreads();
      if (!changed) break;
    }
  }
  __syncthreads();

  int ks = 0;
  for (int k = tid; k < M_PTS; k += 1024) {
    int m = (int)mask[k];
    out[k] = m;
    ks += m;
  }
#pragma unroll
  for (int off = 32; off > 0; off >>= 1) ks += __shfl_down(ks, off, 64);
  if (lane == 0) atomicAdd(&total, ks);
  __syncthreads();
  if (tid == 0) out[out_size - 1] = total;
}

extern "C" void kernel_launch(void* const* d_in, const int* in_sizes, int n_in,
                              void* d_out, int out_size, void* d_ws, size_t ws_size,
                              hipStream_t stream) {
  const float* nodes = (const float*)d_in[0];
  const float* score = (const float*)d_in[1];
  int* out = (int*)d_out;

  char* ws = (char*)d_ws;
  float4* pts = (float4*)ws;
  int* cell_cnt = (int*)(ws + 262144);
  int* cnt = (int*)(ws + 327680);
  unsigned short* cell_list = (unsigned short*)(ws + 393216);
  unsigned short* nbr = (unsigned short*)(ws + 770048);

  bin25<<<GRID_N, 1024, 0, stream>>>(nodes, score, pts, cell_cnt, cell_list);
  wscan<<<2048, 256, 0, stream>>>(pts, cell_cnt, cell_list, cnt, nbr);
  solve_gs<<<1, 1024, 0, stream>>>(pts, cnt, nbr, out, out_size);
}

// Round 16
// 55.534 us; speedup vs baseline: 1.4416x; 1.4416x over previous
//
#include <hip/hip_runtime.h>

// Greedy NMS, M=16384 pts, radius 2.0, torch PairwiseDistance eps=1e-6.
// Output INT32: mask[16384] as 0/1, then count[1].
//
// Round 16: A/B on K3 (K1 bin25 + K2 wscan identical to r11..r15).
//  K3 solve_band (1x1024): r14's batched-read Jacobi body (the proven-fast
//  sweep: independent LDS reads, register entry-state) but organized as 5
//  DESCENDING-SCORE bands with a __syncthreads() between bands. Suppressors
//  live in same-or-earlier bands => ~5 DAG levels propagate per outer sweep
//  => ~5 outer sweeps instead of ~17. Band thresholds equalize ACTIVE
//  population under N(0,1) scores (actives skew low-score). Banding is
//  speed-only; certificate + overflow fallback are distribution-independent.

#define M_PTS    16384
#define RADIUS   2.0f
#define EPS_D    1e-6f
#define GRID_N   25        // 4 m cells over 100 m scene
#define NCELLS   (GRID_N * GRID_N * GRID_N)
#define CELL_CAP 12
#define K_NBR    12
#define CELLS_PB (GRID_N * GRID_N)        // 625 cells per bin-block
#define LIST_PB  (CELLS_PB * CELL_CAP)    // 7500 entries per bin-block
#define BANDS    5
#define BAND_CAP 1024                     // E[~740]/band, sd~26 -> 11 sigma
#define ACT_PAD  (BANDS * BAND_CAP)       // 5120
#define SENT     M_PTS                    // always-0 sentinel byte index

// ws layout (bytes):
//   [0,       262144) float4 pts[16384]
//   [262144,  324644) int    cell_cnt[15625]
//   [327680,  393216) int    cnt[16384]
//   [393216,  768216) ushort cell_list[15625*12]
//   [770048, 1163264) ushort nbr[16384*12]

__device__ __forceinline__ int cell_of(float v) {
  int c = (int)(v * 0.25f);
  return c < 0 ? 0 : (c > GRID_N - 1 ? GRID_N - 1 : c);
}

__device__ __forceinline__ bool edge_test(float4 pi, float4 pj, int j, int i) {
  // j earlier in argsort(-score, stable) AND torch-dist <= radius (exact math)
  bool earlier = (pj.w > pi.w) || ((pj.w == pi.w) && (j < i));
  if (!earlier) return false;
  float ddx = __fadd_rn(__fsub_rn(pi.x, pj.x), EPS_D);
  float ddy = __fadd_rn(__fsub_rn(pi.y, pj.y), EPS_D);
  float ddz = __fadd_rn(__fsub_rn(pi.z, pj.z), EPS_D);
  float d2 = __fadd_rn(__fadd_rn(__fmul_rn(ddx, ddx), __fmul_rn(ddy, ddy)),
                       __fmul_rn(ddz, ddz));
  return !(__fsqrt_rn(d2) > RADIUS);
}

// ---- K1: 25 blocks; block b owns all cells with cx==b (unchanged r11). ----
__global__ __launch_bounds__(1024) void bin25(
    const float* __restrict__ nodes, const float* __restrict__ score,
    float4* __restrict__ pts, int* __restrict__ cell_cnt,
    unsigned short* __restrict__ cell_list) {
  __shared__ int ccnt[CELLS_PB];              // 2.5 KB
  __shared__ unsigned short clist[LIST_PB];   // 15 KB
  const int tid = threadIdx.x;
  const int b   = blockIdx.x;
  if (tid < CELLS_PB) ccnt[tid] = 0;
  __syncthreads();

  for (int i = tid; i < M_PTS; i += 1024) {
    float x = nodes[3 * i + 0];
    if (cell_of(x) != b) continue;
    float y = nodes[3 * i + 1];
    float z = nodes[3 * i + 2];
    float s = score[i];
    pts[i] = make_float4(x, y, z, s);
    int lc = cell_of(y) * GRID_N + cell_of(z);
    int pos = atomicAdd(&ccnt[lc], 1);
    if (pos < CELL_CAP) clist[lc * CELL_CAP + pos] = (unsigned short)i;
  }
  __syncthreads();

  if (tid < CELLS_PB) {
    int v = ccnt[tid];
    cell_cnt[b * CELLS_PB + tid] = v > CELL_CAP ? CELL_CAP : v;
  }
  for (int e = tid; e < LIST_PB; e += 1024)
    cell_list[b * LIST_PB + e] = clist[e];
}

// ---- K2: 2 points/wave, one cell/lane (unchanged r10/r11). ----
__global__ __launch_bounds__(256) void wscan(
    const float4* __restrict__ pts, const int* __restrict__ cell_cnt,
    const unsigned short* __restrict__ cell_list,
    int* __restrict__ cnt, unsigned short* __restrict__ nbr) {
  const int tid  = threadIdx.x;
  const int lane = tid & 63;
  const int d    = lane & 31;
  const int half = lane >> 5;
  const int gwave = (blockIdx.x * 256 + tid) >> 6;
  const int i = gwave * 2 + half;

  const float4 pi = pts[i];
  int n = 0, cid = 0, m = 0, firstj = 0;
  if (d < 27) {
    int cx = cell_of(pi.x) + d / 9 - 1;
    int cy = cell_of(pi.y) + (d / 3) % 3 - 1;
    int cz = cell_of(pi.z) + d % 3 - 1;
    if (cx >= 0 && cx < GRID_N && cy >= 0 && cy < GRID_N &&
        cz >= 0 && cz < GRID_N) {
      cid = (cx * GRID_N + cy) * GRID_N + cz;
      m = cell_cnt[cid];
      for (int s = 0; s < m; ++s) {
        int j = cell_list[cid * CELL_CAP + s];
        if (edge_test(pi, pts[j], j, i)) { if (!n) firstj = j; ++n; }
      }
    }
  }
  int x = n;
#pragma unroll
  for (int off = 1; off < 32; off <<= 1) {
    int y = __shfl_up(x, off, 32);
    if (d >= off) x += y;
  }
  int excl = x - n;
  int tot = __shfl(x, 31, 32);
  if (n == 1) {
    if (excl < K_NBR) nbr[i * K_NBR + excl] = (unsigned short)firstj;
  } else if (n > 1) {
    int pos = excl;
    for (int s = 0; s < m && pos < K_NBR; ++s) {
      int j = cell_list[cid * CELL_CAP + s];
      if (edge_test(pi, pts[j], j, i)) {
        nbr[i * K_NBR + pos] = (unsigned short)j;
        ++pos;
      }
    }
  }
  if (d == 0) cnt[i] = tot > K_NBR ? K_NBR : tot;
}

// ---- K3: 5-band barrier-separated batched Jacobi ----
__global__ __launch_bounds__(1024) void solve_band(
    const float4* __restrict__ pts, const int* __restrict__ cnt,
    const unsigned short* __restrict__ nbr,
    int* __restrict__ out, int out_size) {
  __shared__ unsigned char mask[M_PTS + 4];  // +sentinel (index SENT == 0)
  __shared__ unsigned int act[ACT_PAD];      // 20 KB: k | (c<<16)
  __shared__ int bn[BANDS];
  __shared__ int total;

  const int tid = threadIdx.x;
  const int lane = tid & 63;
  if (tid == 0) total = 0;
  if (tid < BANDS) bn[tid] = 0;
  unsigned int* mask4 = (unsigned int*)mask;
  for (int w = tid; w < M_PTS / 4; w += 1024) mask4[w] = 0x01010101u;
  if (tid == 0) mask4[M_PTS / 4] = 0u;       // sentinel byte = 0
  for (int a = tid; a < ACT_PAD; a += 1024) act[a] = 0u;  // c=0 sentinels
  __syncthreads();

  // banded ballot compaction. Thresholds chosen so ACTIVE points split
  // ~equally across 5 descending-score bands for N(0,1) scores (actives
  // skew low-score). Speed heuristic only.
  bool ovf = false;
  for (int k = tid; k < M_PTS; k += 1024) {
    int c = cnt[k];
    if (c > K_NBR) c = K_NBR;
    float s = pts[k].w;
    int band = (s > 0.2019f) ? 0 : (s > -0.2793f) ? 1
             : (s > -0.6903f) ? 2 : (s > -1.2004f) ? 3 : 4;
#pragma unroll
    for (int b = 0; b < BANDS; ++b) {
      bool sel = (c > 0) && (band == b);
      unsigned long long bal = __ballot(sel);
      if (!bal) continue;
      int wcnt = __popcll(bal);
      int wbase = 0;
      if (lane == 0) wbase = atomicAdd(&bn[b], wcnt);
      wbase = __shfl(wbase, 0, 64);
      if (sel) {
        int pos = wbase + __popcll(bal & ((1ull << lane) - 1ull));
        if (pos < BAND_CAP) act[b * BAND_CAP + pos] = (unsigned)k | ((unsigned)c << 16);
        else ovf = true;
      }
    }
  }
  __syncthreads();
  bool okl = (bn[0] <= BAND_CAP) && (bn[1] <= BAND_CAP) && (bn[2] <= BAND_CAP) &&
             (bn[3] <= BAND_CAP) && (bn[4] <= BAND_CAP) && !ovf;
  const bool ok = (__syncthreads_count(okl) == 1024);

  // stage: entry e of this thread = band e, slot tid (absent -> c=0 sentinel)
  unsigned ae[BANDS];
  unsigned short r0[BANDS], r1[BANDS], r2[BANDS];
  int cur[BANDS];
#pragma unroll
  for (int e = 0; e < BANDS; ++e) {
    unsigned v = act[e * BAND_CAP + tid];
    ae[e] = v;
    int k = (int)(v & 0xFFFFu);
    int c = (int)(v >> 16);
    const unsigned short* row = nbr + (size_t)k * K_NBR;
    unsigned w = (c > 0) ? *(const unsigned int*)row : 0u;   // r0 | r1<<16
    r0[e] = (c > 0) ? (unsigned short)(w & 0xFFFFu) : (unsigned short)SENT;
    r1[e] = (c > 1) ? (unsigned short)(w >> 16)     : (unsigned short)SENT;
    r2[e] = (c > 2) ? row[2]                        : (unsigned short)SENT;
    cur[e] = 1;
  }
  __syncthreads();

  if (ok) {
    for (int it = 0; it < 64; ++it) {
      int any = 0;
#pragma unroll
      for (int e = 0; e < BANDS; ++e) {
        // batched independent reads for THIS band (visibility of earlier
        // bands' writes guaranteed by the barrier below)
        unsigned v = ae[e];
        int c = (int)(v >> 16);
        int m0 = (int)mask[r0[e]];
        int m1 = (int)mask[r1[e]];
        int m2 = (int)mask[r2[e]];
        if (c) {
          int kp = (m0 ^ 1) & (m1 ^ 1) & (m2 ^ 1);
          if (c > 3) {   // ~0.2% of actives: global tail
            int k = (int)(v & 0xFFFFu);
            const unsigned short* row = nbr + (size_t)k * K_NBR;
            for (int t = 3; t < c; ++t) kp &= (int)mask[row[t]] ^ 1;
          }
          if (kp != cur[e]) {
            cur[e] = kp;
            mask[v & 0xFFFFu] = (unsigned char)kp;   // single writer
            any = 1;
          }
        }
        __syncthreads();   // band e's writes visible to band e+1 (uniform)
      }
      // zero writes across a full sweep => f(S)=S => unique DAG fixpoint
      if (__syncthreads_count(any) == 0) break;
    }
  } else {
    // overflow fallback (statistically never): barriered global sweeps
    __shared__ int changed;
    for (int it = 0; it < 512; ++it) {
      if (tid == 0) changed = 0;
      __syncthreads();
      int any = 0;
      for (int k = tid; k < M_PTS; k += 1024) {
        int c = cnt[k]; if (c > K_NBR) c = K_NBR;
        if (!c) continue;
        int kp = 1;
        for (int t = 0; t < c; ++t) kp &= (int)mask[nbr[k * K_NBR + t]] ^ 1;
        if (kp != (int)mask[k]) { mask[k] = (unsigned char)kp; any = 1; }
      }
      if (any) changed = 1;
      __syncthreads();
      if (!changed) break;
    }
  }
  __syncthreads();

  int ks = 0;
  for (int k = tid; k < M_PTS; k += 1024) {
    int m = (int)mask[k];
    out[k] = m;
    ks += m;
  }
#pragma unroll
  for (int off = 32; off > 0; off >>= 1) ks += __shfl_down(ks, off, 64);
  if (lane == 0) atomicAdd(&total, ks);
  __syncthreads();
  if (tid == 0) out[out_size - 1] = total;
}

extern "C" void kernel_launch(void* const* d_in, const int* in_sizes, int n_in,
                              void* d_out, int out_size, void* d_ws, size_t ws_size,
                              hipStream_t stream) {
  const float* nodes = (const float*)d_in[0];
  const float* score = (const float*)d_in[1];
  int* out = (int*)d_out;

  char* ws = (char*)d_ws;
  float4* pts = (float4*)ws;
  int* cell_cnt = (int*)(ws + 262144);
  int* cnt = (int*)(ws + 327680);
  unsigned short* cell_list = (unsigned short*)(ws + 393216);
  unsigned short* nbr = (unsigned short*)(ws + 770048);

  bin25<<<GRID_N, 1024, 0, stream>>>(nodes, score, pts, cell_cnt, cell_list);
  wscan<<<2048, 256, 0, stream>>>(pts, cell_cnt, cell_list, cnt, nbr);
  solve_band<<<1, 1024, 0, stream>>>(pts, cnt, nbr, out, out_size);
}

// Round 17
// 44.729 us; speedup vs baseline: 1.7898x; 1.2416x over previous
//
#include <hip/hip_runtime.h>

// Greedy NMS, M=16384 pts, radius 2.0, torch PairwiseDistance eps=1e-6.
// Output INT32: mask[16384] as 0/1, then count[1].
//
// Round 17: A/B on K3 (K1 bin25 + K2 wscan identical to r11..r16).
//  K3 solve_cc (1x1024): chain-compression solve. 87% of active nodes have
//  exactly 1 earlier-neighbor => val[k] = val[parent]^1. One-time pointer
//  walks collapse c=1 chains to constants (terminus c=0) or (backbone,parity)
//  refs. Only the ~520 c>=2 "backbone" nodes iterate (1/thread, terms in
//  registers, depth ~4) -> sweeps shrink 17x in count AND 5x in LDS traffic.
//  Any cap overflow sets fail -> proven full-sweep fallback. Deterministic.

#define M_PTS    16384
#define RADIUS   2.0f
#define EPS_D    1e-6f
#define GRID_N   25        // 4 m cells over 100 m scene
#define NCELLS   (GRID_N * GRID_N * GRID_N)
#define CELL_CAP 12
#define K_NBR    12
#define CELLS_PB (GRID_N * GRID_N)        // 625 cells per bin-block
#define LIST_PB  (CELLS_PB * CELL_CAP)    // 7500 entries per bin-block
#define SENT     M_PTS                    // val[SENT]=0 sentinel
#define BB_CAP   1024                     // E[backbone]~520, ~21 sigma
#define DFR_CAP  2048                     // E[deferred]~200

// ws layout (bytes):
//   [0,       262144) float4 pts[16384]
//   [262144,  324644) int    cell_cnt[15625]
//   [327680,  393216) int    cnt[16384]
//   [393216,  768216) ushort cell_list[15625*12]
//   [770048, 1163264) ushort nbr[16384*12]

__device__ __forceinline__ int cell_of(float v) {
  int c = (int)(v * 0.25f);
  return c < 0 ? 0 : (c > GRID_N - 1 ? GRID_N - 1 : c);
}

__device__ __forceinline__ bool edge_test(float4 pi, float4 pj, int j, int i) {
  // j earlier in argsort(-score, stable) AND torch-dist <= radius (exact math)
  bool earlier = (pj.w > pi.w) || ((pj.w == pi.w) && (j < i));
  if (!earlier) return false;
  float ddx = __fadd_rn(__fsub_rn(pi.x, pj.x), EPS_D);
  float ddy = __fadd_rn(__fsub_rn(pi.y, pj.y), EPS_D);
  float ddz = __fadd_rn(__fsub_rn(pi.z, pj.z), EPS_D);
  float d2 = __fadd_rn(__fadd_rn(__fmul_rn(ddx, ddx), __fmul_rn(ddy, ddy)),
                       __fmul_rn(ddz, ddz));
  return !(__fsqrt_rn(d2) > RADIUS);
}

// ---- K1: 25 blocks; block b owns all cells with cx==b (unchanged r11). ----
__global__ __launch_bounds__(1024) void bin25(
    const float* __restrict__ nodes, const float* __restrict__ score,
    float4* __restrict__ pts, int* __restrict__ cell_cnt,
    unsigned short* __restrict__ cell_list) {
  __shared__ int ccnt[CELLS_PB];              // 2.5 KB
  __shared__ unsigned short clist[LIST_PB];   // 15 KB
  const int tid = threadIdx.x;
  const int b   = blockIdx.x;
  if (tid < CELLS_PB) ccnt[tid] = 0;
  __syncthreads();

  for (int i = tid; i < M_PTS; i += 1024) {
    float x = nodes[3 * i + 0];
    if (cell_of(x) != b) continue;
    float y = nodes[3 * i + 1];
    float z = nodes[3 * i + 2];
    float s = score[i];
    pts[i] = make_float4(x, y, z, s);
    int lc = cell_of(y) * GRID_N + cell_of(z);
    int pos = atomicAdd(&ccnt[lc], 1);
    if (pos < CELL_CAP) clist[lc * CELL_CAP + pos] = (unsigned short)i;
  }
  __syncthreads();

  if (tid < CELLS_PB) {
    int v = ccnt[tid];
    cell_cnt[b * CELLS_PB + tid] = v > CELL_CAP ? CELL_CAP : v;
  }
  for (int e = tid; e < LIST_PB; e += 1024)
    cell_list[b * LIST_PB + e] = clist[e];
}

// ---- K2: 2 points/wave, one cell/lane (unchanged r10/r11). ----
__global__ __launch_bounds__(256) void wscan(
    const float4* __restrict__ pts, const int* __restrict__ cell_cnt,
    const unsigned short* __restrict__ cell_list,
    int* __restrict__ cnt, unsigned short* __restrict__ nbr) {
  const int tid  = threadIdx.x;
  const int lane = tid & 63;
  const int d    = lane & 31;
  const int half = lane >> 5;
  const int gwave = (blockIdx.x * 256 + tid) >> 6;
  const int i = gwave * 2 + half;

  const float4 pi = pts[i];
  int n = 0, cid = 0, m = 0, firstj = 0;
  if (d < 27) {
    int cx = cell_of(pi.x) + d / 9 - 1;
    int cy = cell_of(pi.y) + (d / 3) % 3 - 1;
    int cz = cell_of(pi.z) + d % 3 - 1;
    if (cx >= 0 && cx < GRID_N && cy >= 0 && cy < GRID_N &&
        cz >= 0 && cz < GRID_N) {
      cid = (cx * GRID_N + cy) * GRID_N + cz;
      m = cell_cnt[cid];
      for (int s = 0; s < m; ++s) {
        int j = cell_list[cid * CELL_CAP + s];
        if (edge_test(pi, pts[j], j, i)) { if (!n) firstj = j; ++n; }
      }
    }
  }
  int x = n;
#pragma unroll
  for (int off = 1; off < 32; off <<= 1) {
    int y = __shfl_up(x, off, 32);
    if (d >= off) x += y;
  }
  int excl = x - n;
  int tot = __shfl(x, 31, 32);
  if (n == 1) {
    if (excl < K_NBR) nbr[i * K_NBR + excl] = (unsigned short)firstj;
  } else if (n > 1) {
    int pos = excl;
    for (int s = 0; s < m && pos < K_NBR; ++s) {
      int j = cell_list[cid * CELL_CAP + s];
      if (edge_test(pi, pts[j], j, i)) {
        nbr[i * K_NBR + pos] = (unsigned short)j;
        ++pos;
      }
    }
  }
  if (d == 0) cnt[i] = tot > K_NBR ? K_NBR : tot;
}

// ---- K3: chain-compression solve ----
__global__ __launch_bounds__(1024) void solve_cc(
    const int* __restrict__ cnt, const unsigned short* __restrict__ nbr,
    int* __restrict__ out, int out_size) {
  __shared__ unsigned int pack[M_PTS];      // 64 KB: c | r0<<4
  __shared__ unsigned char val[M_PTS + 4];  // 16 KB: 0xFF unknown, else 0/1
  __shared__ unsigned short bb[BB_CAP];     // 2 KB backbone ids
  __shared__ unsigned int dfr[DFR_CAP];     // 8 KB k|t<<14|par<<28
  __shared__ int nbb, ndfr, total, fail;

  const int tid = threadIdx.x;
  const int lane = tid & 63;
  if (tid == 0) { nbb = 0; ndfr = 0; total = 0; fail = 0; }

  // P0: pack table + val init
  for (int k = tid; k < M_PTS; k += 1024) {
    int c = cnt[k]; if (c > K_NBR) c = K_NBR;
    unsigned r0 = (c > 0) ? (unsigned)nbr[(size_t)k * K_NBR] : 0u;
    pack[k] = (unsigned)c | (r0 << 4);
    val[k] = (c == 0) ? 1 : 0xFF;
  }
  if (tid == 0) val[SENT] = 0;
  __syncthreads();

  // P1: compact backbone (c>=2) + walk c==1 chains (static table => det.)
  for (int k = tid; k < M_PTS; k += 1024) {
    int c = (int)(pack[k] & 15u);
    bool isbb = (c >= 2);
    unsigned long long bal = __ballot(isbb);
    if (bal) {
      int wcnt = __popcll(bal);
      int wbase = 0;
      if (lane == 0) wbase = atomicAdd(&nbb, wcnt);
      wbase = __shfl(wbase, 0, 64);
      if (isbb) {
        int pos = wbase + __popcll(bal & ((1ull << lane) - 1ull));
        if (pos < BB_CAP) bb[pos] = (unsigned short)k; else fail = 1;
      }
    }
    if (c == 1) {
      int j = (int)(pack[k] >> 4);
      int parity = 1, steps = 0;
      while ((pack[j] & 15u) == 1u && steps < 64) {
        j = (int)(pack[j] >> 4); parity ^= 1; ++steps;
      }
      unsigned cj = pack[j] & 15u;
      if (cj == 0u) val[k] = (unsigned char)(1 ^ parity);   // constant now
      else if (cj == 1u) fail = 1;                          // walk cap (never)
      else {
        int pos = atomicAdd(&ndfr, 1);
        if (pos < DFR_CAP)
          dfr[pos] = (unsigned)k | ((unsigned)j << 14) | ((unsigned)parity << 28);
        else fail = 1;
      }
    }
  }
  __syncthreads();

  const int NBB = nbb < BB_CAP ? nbb : BB_CAP;
  const int NDFR = ndfr < DFR_CAP ? ndfr : DFR_CAP;

  // P2: backbone staging — thread tid owns bb[tid]; terms in named registers.
  // term for parent p: !val[p] = val[terminus] ^ (parity^1); constants folded.
  int ownk = -1, resolved = 1;
  unsigned short tt0 = SENT, tt1 = SENT, tt2 = SENT;
  int q0 = 1, q1 = 1, q2 = 1;    // SENT,q=1 => term = 0^1 = 1 (neutral)
  if (!fail && tid < NBB) {
    ownk = bb[tid];
    int c = (int)(pack[ownk] & 15u);
    const unsigned short* row = nbr + (size_t)ownk * K_NBR;
    int dead = 0, nu = 0, lfail = 0;
    for (int t = 0; t < c; ++t) {
      int p = row[t];
      int v = val[p];
      if (v != 0xFF) {
        if (v == 1) dead = 1;              // kept parent => suppressed (term 0)
      } else {
        int cp = (int)(pack[p] & 15u);
        int tgt = p, par = 0;
        if (cp == 1) {
          int j = (int)(pack[p] >> 4);
          par = 1;
          int steps = 0;
          while ((pack[j] & 15u) == 1u && steps < 64) {
            j = (int)(pack[j] >> 4); par ^= 1; ++steps;
          }
          unsigned cj = pack[j] & 15u;
          if (cj == 1u) { lfail = 1; tgt = -1; }
          else if (cj == 0u) { if (par == 0) dead = 1; tgt = -1; }  // term=par
          else tgt = j;
        }
        if (tgt >= 0) {
          int q = par ^ 1;                 // term = val[tgt] ^ q
          if (nu == 0)      { tt0 = (unsigned short)tgt; q0 = q; }
          else if (nu == 1) { tt1 = (unsigned short)tgt; q1 = q; }
          else if (nu == 2) { tt2 = (unsigned short)tgt; q2 = q; }
          else lfail = 1;
          ++nu;
        }
      }
    }
    if (lfail) fail = 1;
    else if (dead) val[ownk] = 0;
    else if (nu == 0) val[ownk] = 1;
    else resolved = 0;
  }
  __syncthreads();

  // P3: backbone sweeps (~depth iterations, 3 LDS byte reads/thread)
  if (!fail) {
    for (int it = 0; it < 64; ++it) {
      int unres = 0;
      if (!resolved) {
        int v0 = val[tt0], v1 = val[tt1], v2 = val[tt2];   // batched reads
        int kn0 = (v0 != 0xFF), kn1 = (v1 != 0xFF), kn2 = (v2 != 0xFF);
        int t0 = v0 ^ q0, t1 = v1 ^ q1, t2 = v2 ^ q2;
        if ((kn0 && t0 == 0) || (kn1 && t1 == 0) || (kn2 && t2 == 0)) {
          val[ownk] = 0; resolved = 1;              // AND short-circuit
        } else if (kn0 && kn1 && kn2) {
          val[ownk] = (unsigned char)(t0 & t1 & t2); resolved = 1;
        } else unres = 1;
      }
      if (__syncthreads_count(unres) == 0) break;
    }
    if (!resolved) fail = 1;   // 64 sweeps without resolution (never on a DAG)
  }
  __syncthreads();

  // P4: apply deferred chain refs (targets now resolved)
  if (!fail) {
    for (int idx = tid; idx < NDFR; idx += 1024) {
      unsigned e = dfr[idx];
      int k = (int)(e & 0x3FFFu);
      int t = (int)((e >> 14) & 0x3FFFu);
      int par = (int)(e >> 28);
      val[k] = (unsigned char)(val[t] ^ par);
    }
  }
  __syncthreads();

  // P5: fallback (any cap overflow / non-convergence — statistically never):
  // full barriered Jacobi from all-kept using global nbr rows.
  if (fail) {
    for (int k = tid; k < M_PTS; k += 1024) val[k] = 1;
    __syncthreads();
    __shared__ int changed;
    for (int it = 0; it < 512; ++it) {
      if (tid == 0) changed = 0;
      __syncthreads();
      int any = 0;
      for (int k = tid; k < M_PTS; k += 1024) {
        int c = (int)(pack[k] & 15u);
        if (!c) continue;
        int kp = 1;
        const unsigned short* row = nbr + (size_t)k * K_NBR;
        for (int t = 0; t < c; ++t) kp &= (int)val[row[t]] ^ 1;
        if (kp != (int)val[k]) { val[k] = (unsigned char)kp; any = 1; }
      }
      if (any) changed = 1;
      __syncthreads();
      if (!changed) break;
    }
    __syncthreads();
  }

  // P6: output + count
  int ks = 0;
  for (int k = tid; k < M_PTS; k += 1024) {
    int m = (int)val[k];
    out[k] = m;
    ks += m;
  }
#pragma unroll
  for (int off = 32; off > 0; off >>= 1) ks += __shfl_down(ks, off, 64);
  if (lane == 0) atomicAdd(&total, ks);
  __syncthreads();
  if (tid == 0) out[out_size - 1] = total;
}

extern "C" void kernel_launch(void* const* d_in, const int* in_sizes, int n_in,
                              void* d_out, int out_size, void* d_ws, size_t ws_size,
                              hipStream_t stream) {
  const float* nodes = (const float*)d_in[0];
  const float* score = (const float*)d_in[1];
  int* out = (int*)d_out;

  char* ws = (char*)d_ws;
  float4* pts = (float4*)ws;
  int* cell_cnt = (int*)(ws + 262144);
  int* cnt = (int*)(ws + 327680);
  unsigned short* cell_list = (unsigned short*)(ws + 393216);
  unsigned short* nbr = (unsigned short*)(ws + 770048);

  bin25<<<GRID_N, 1024, 0, stream>>>(nodes, score, pts, cell_cnt, cell_list);
  wscan<<<2048, 256, 0, stream>>>(pts, cell_cnt, cell_list, cnt, nbr);
  solve_cc<<<1, 1024, 0, stream>>>(cnt, nbr, out, out_size);
}